// Round 2
// baseline (128.366 us; speedup 1.0000x reference)
//
#include <hip/hip_runtime.h>

// BayesPosLinear: out[s,b,o] = sum_i input[s,b,i] * exp(w_mu[o,i] + softplus(w_std_eta[o,i])*eps_w[b,o,i])
//                 + (b_mu[o] + softplus(b_std_eta[o])*eps_b[b,o])
// plus KL(w), KL(b) scalars.
// S=16, B=32, IN=1024, OUT=1024. Memory floor: eps_w 134 MB stream.
//
// R1 structure: lane = o_local*16 + iq. Each lane owns one o and 1/16 of i,
// accumulates all 16 s in regs -> reduction is 4 butterfly steps within
// 16-lane groups (vs 6 steps x 64 values before). 16 waves/CU, deep unroll
// for outstanding HBM loads.

constexpr int S_ = 16, B_ = 32, IN_ = 1024, OUT_ = 1024;

__device__ __forceinline__ float softplus_f(float x) {
    float e = __expf(-fabsf(x));
    return fmaxf(x, 0.0f) + __logf(1.0f + e);
}

// grid: 2048 blocks (8 xcd x 32 b x 8 osub), 256 threads (4 waves x 4 o each)
__global__ __launch_bounds__(256, 4) void bpl_main_kernel(
    const float* __restrict__ input,   // [S,B,IN]
    const float* __restrict__ w_mu,    // [OUT,IN]
    const float* __restrict__ w_eta,   // [OUT,IN]
    const float* __restrict__ b_mu,    // [OUT]
    const float* __restrict__ b_eta,   // [OUT]
    const float* __restrict__ eps_w,   // [B,OUT,IN]
    const float* __restrict__ eps_b,   // [B,OUT]
    float* __restrict__ out)           // [S,B,OUT]
{
    __shared__ float res[16][17];      // [s][o_local], padded

    const int blk  = blockIdx.x;
    const int xcd  = blk & 7;          // OUT-eighth -> XCD-local L2 working set
    const int rest = blk >> 3;
    const int b    = rest & 31;
    const int osub = rest >> 5;        // 0..7
    const int o_base = xcd * 128 + osub * 16;

    const int tid  = threadIdx.x;
    const int wid  = tid >> 6;
    const int lane = tid & 63;
    const int ol   = lane >> 4;        // o within wave: 0..3
    const int iq   = lane & 15;        // i-sixteenth: 0..15
    const int o    = o_base + wid * 4 + ol;

    const float* __restrict__ mu_p = w_mu  + (size_t)o * IN_;
    const float* __restrict__ et_p = w_eta + (size_t)o * IN_;
    const float* __restrict__ ep_p = eps_w + ((size_t)b * OUT_ + o) * IN_;
    const float* __restrict__ in_p = input + (size_t)b * IN_;   // + s*B*IN + i

    float acc[16];
    #pragma unroll
    for (int s = 0; s < 16; ++s) acc[s] = 0.0f;

    #pragma unroll 4
    for (int it = 0; it < 16; ++it) {
        const int i0 = it * 64 + iq * 4;   // 16 lanes/o-row -> 256B contiguous

        const float4 mu = *reinterpret_cast<const float4*>(mu_p + i0);
        const float4 et = *reinterpret_cast<const float4*>(et_p + i0);
        const float4 ep = *reinterpret_cast<const float4*>(ep_p + i0);

        const float w0 = __expf(fmaf(1e-6f + softplus_f(et.x), ep.x, mu.x));
        const float w1 = __expf(fmaf(1e-6f + softplus_f(et.y), ep.y, mu.y));
        const float w2 = __expf(fmaf(1e-6f + softplus_f(et.z), ep.z, mu.z));
        const float w3 = __expf(fmaf(1e-6f + softplus_f(et.w), ep.w, mu.w));

        #pragma unroll
        for (int s = 0; s < 16; ++s) {
            const float4 v = *reinterpret_cast<const float4*>(
                in_p + (size_t)s * (B_ * IN_) + i0);
            float a = acc[s];
            a = fmaf(v.x, w0, a);
            a = fmaf(v.y, w1, a);
            a = fmaf(v.z, w2, a);
            a = fmaf(v.w, w3, a);
            acc[s] = a;
        }
    }

    // reduce each acc[s] across the 16-lane iq group (4 butterfly steps)
    #pragma unroll
    for (int s = 0; s < 16; ++s) {
        float v = acc[s];
        v += __shfl_xor(v, 1, 16);
        v += __shfl_xor(v, 2, 16);
        v += __shfl_xor(v, 4, 16);
        v += __shfl_xor(v, 8, 16);
        acc[s] = v;
    }

    // lane iq takes s=iq (static cndmask chain, no scratch)
    float mine = acc[0];
    #pragma unroll
    for (int s = 1; s < 16; ++s) mine = (iq == s) ? acc[s] : mine;

    res[iq][wid * 4 + ol] = mine;
    __syncthreads();

    // coalesced store with fused bias: thread t -> (s = t>>4, o_local = t&15)
    const int s  = tid >> 4;
    const int olx = tid & 15;
    const int oo  = o_base + olx;
    const float bias = fmaf(1e-6f + softplus_f(b_eta[oo]), eps_b[(size_t)b * OUT_ + oo], b_mu[oo]);
    out[(size_t)(s * B_ + b) * OUT_ + oo] = res[s][olx] + bias;
}

// ---------------- KL reduction kernel ----------------
__global__ __launch_bounds__(256) void bpl_kl_kernel(
    const float* __restrict__ w_mu, const float* __restrict__ w_eta,
    const float* __restrict__ b_mu, const float* __restrict__ b_eta,
    float* __restrict__ kl)            // kl[0]=kl_w, kl[1]=kl_b (pre-zeroed)
{
    __shared__ float red[4];
    const int tid  = threadIdx.x;
    const int wid  = tid >> 6;
    const int lane = tid & 63;

    const size_t base = (size_t)blockIdx.x * IN_ + tid * 4;
    const float4 mu = *reinterpret_cast<const float4*>(&w_mu[base]);
    const float4 et = *reinterpret_cast<const float4*>(&w_eta[base]);

    float local = 0.0f;
    {
        const float m[4] = {mu.x, mu.y, mu.z, mu.w};
        const float e[4] = {et.x, et.y, et.z, et.w};
        #pragma unroll
        for (int j = 0; j < 4; ++j) {
            const float sd = 1e-6f + softplus_f(e[j]);
            local += -__logf(sd) + 0.5f * fmaf(sd, sd, m[j] * m[j]) - 0.5f;
        }
    }
    #pragma unroll
    for (int off = 32; off > 0; off >>= 1) local += __shfl_xor(local, off, 64);
    if (lane == 0) red[wid] = local;
    __syncthreads();
    if (tid == 0) atomicAdd(&kl[0], red[0] + red[1] + red[2] + red[3]);

    if (blockIdx.x != 0) return;

    // kl_b: 1024 elems, 4 per thread
    float lb = 0.0f;
    #pragma unroll
    for (int j = 0; j < 4; ++j) {
        const int idx = tid * 4 + j;
        const float sd = 1e-6f + softplus_f(b_eta[idx]);
        const float m  = b_mu[idx];
        lb += -__logf(sd) + 0.5f * fmaf(sd, sd, m * m) - 0.5f;
    }
    #pragma unroll
    for (int off = 32; off > 0; off >>= 1) lb += __shfl_xor(lb, off, 64);
    __syncthreads();
    if (lane == 0) red[wid] = lb;
    __syncthreads();
    if (tid == 0) atomicAdd(&kl[1], red[0] + red[1] + red[2] + red[3]);
}

extern "C" void kernel_launch(void* const* d_in, const int* in_sizes, int n_in,
                              void* d_out, int out_size, void* d_ws, size_t ws_size,
                              hipStream_t stream)
{
    const float* input = (const float*)d_in[0];
    const float* w_mu  = (const float*)d_in[1];
    const float* w_eta = (const float*)d_in[2];
    const float* b_mu  = (const float*)d_in[3];
    const float* b_eta = (const float*)d_in[4];
    const float* eps_w = (const float*)d_in[5];
    const float* eps_b = (const float*)d_in[6];

    float* out = (float*)d_out;
    float* kl  = out + (size_t)S_ * B_ * OUT_;   // offsets 524288, 524289

    hipMemsetAsync(kl, 0, 2 * sizeof(float), stream);
    bpl_kl_kernel<<<1024, 256, 0, stream>>>(w_mu, w_eta, b_mu, b_eta, kl);
    bpl_main_kernel<<<2048, 256, 0, stream>>>(input, w_mu, w_eta, b_mu, b_eta, eps_w, eps_b, out);
}

// Round 3
// 72.518 us; speedup vs baseline: 1.7701x; 1.7701x over previous
//
#include <hip/hip_runtime.h>

// BayesPosLinear: out[s,b,o] = sum_i input[s,b,i] * exp(w_mu[o,i] + (1e-6+softplus(w_std_eta[o,i]))*eps_w[b,o,i])
//                 + (b_mu[o] + (1e-6+softplus(b_std_eta[o]))*eps_b[b,o])
// plus KL(w), KL(b) scalars (fused into main kernel, atomicAdd).
// S=16, B=32, IN=1024, OUT=1024. HBM floor: eps_w 134 MB stream + tables 8 MB ~ 23 us.
//
// R2 structure:
//  - 512 blocks (8 xcd * 2 ohi * 32 b), 512 threads (8 waves); exactly 2 blocks/CU, no tail.
//  - input[b] (16 s x 1024 i = 64KB f32) staged ONCE per block into LDS; inner-loop input
//    reads are broadcast ds_read_b128 (128B unique, conflict-free).
//  - wave = 8 o x 8 iq; lane owns one o and a 1/8 i-slice; acc[16] (one per s) in regs.
//  - per it: only 3 independent streaming dwordx4 (mu, eta, eps); unroll 4 -> 12 in flight.
//  - epilogue: 3-step shuffle reduce within 8-lane groups, LDS transpose (overlaid on the
//    input buffer), coalesced stores with fused bias.
//  - KL_w computed by the b==0 blocks while they stream mu/eta (saves an 8MB re-read);
//    KL_b by block 0. atomicAdd into kl[0..1] (memset to 0 each launch).

constexpr int S_ = 16, B_ = 32, IN_ = 1024, OUT_ = 1024;

__device__ __forceinline__ float softplus_f(float x) {
    // stable for any x (used for b_eta which straddles 0)
    float e = __expf(-fabsf(x));
    return fmaxf(x, 0.0f) + __logf(1.0f + e);
}

__global__ __launch_bounds__(512, 4) void bpl_main_kernel(
    const float* __restrict__ input,   // [S,B,IN]
    const float* __restrict__ w_mu,    // [OUT,IN]
    const float* __restrict__ w_eta,   // [OUT,IN]  (range [-4,-2] per setup)
    const float* __restrict__ b_mu,    // [OUT]
    const float* __restrict__ b_eta,   // [OUT]
    const float* __restrict__ eps_w,   // [B,OUT,IN]
    const float* __restrict__ eps_b,   // [B,OUT]
    float* __restrict__ out,           // [S,B,OUT]
    float* __restrict__ kl)            // kl[0]=kl_w, kl[1]=kl_b (pre-zeroed)
{
    __shared__ float smem[16384];      // 64KB: input[s][i]; later overlaid by res[16][72] @0 and kl partials @1200

    const int blk  = blockIdx.x;
    const int xcd  = blk & 7;          // XCD-local o-slice -> w tables (1MB/XCD) stay L2-resident
    const int rest = blk >> 3;         // 0..63
    const int b    = rest & 31;
    const int ohi  = rest >> 5;        // 0..1
    const int o_base = (xcd * 2 + ohi) * 64;

    const int tid  = threadIdx.x;
    const int wid  = tid >> 6;         // 0..7
    const int lane = tid & 63;
    const int og   = lane >> 3;        // o-subgroup within wave: 0..7
    const int iq   = lane & 7;         // i-eighth: 0..7
    const int o    = o_base + wid * 8 + og;

    // ---- stage input[b] into LDS (once) ----
    {
        const int s = tid >> 5, c = tid & 31;                // 32 threads per s-row
        const float* __restrict__ src = input + ((size_t)s * B_ + b) * IN_;
        float* dst = smem + s * 1024;
        #pragma unroll
        for (int j = 0; j < 8; ++j) {
            const int i = c * 4 + j * 128;                   // 512B contiguous per j per 32 threads
            *reinterpret_cast<float4*>(&dst[i]) =
                *reinterpret_cast<const float4*>(&src[i]);
        }
    }
    __syncthreads();

    const float* __restrict__ mu_p = w_mu  + (size_t)o * IN_;
    const float* __restrict__ et_p = w_eta + (size_t)o * IN_;
    const float* __restrict__ ep_p = eps_w + ((size_t)b * OUT_ + o) * IN_;

    const bool do_kl = (b == 0);
    float klw = 0.0f;

    float acc[16];
    #pragma unroll
    for (int s = 0; s < 16; ++s) acc[s] = 0.0f;

    #pragma unroll 4
    for (int it = 0; it < 32; ++it) {
        const int i0 = it * 32 + iq * 4;    // 8 lanes/o-row -> 128B contiguous per o-group

        const float4 muv = *reinterpret_cast<const float4*>(mu_p + i0);
        const float4 etv = *reinterpret_cast<const float4*>(et_p + i0);
        const float4 epv = *reinterpret_cast<const float4*>(ep_p + i0);
        const float mua[4] = {muv.x, muv.y, muv.z, muv.w};
        const float eta[4] = {etv.x, etv.y, etv.z, etv.w};
        const float epa[4] = {epv.x, epv.y, epv.z, epv.w};

        float w[4];
        #pragma unroll
        for (int j = 0; j < 4; ++j) {
            // w_eta < 0 guaranteed -> softplus(x) = log1p(exp(x)) directly
            const float sp = __logf(1.0f + __expf(eta[j])) + 1e-6f;
            w[j] = __expf(fmaf(sp, epa[j], mua[j]));
            if (do_kl)
                klw += -__logf(sp) + 0.5f * fmaf(sp, sp, mua[j] * mua[j]) - 0.5f;
        }

        #pragma unroll
        for (int s = 0; s < 16; ++s) {
            const float4 v = *reinterpret_cast<const float4*>(&smem[s * 1024 + i0]);
            float a = acc[s];
            a = fmaf(v.x, w[0], a);
            a = fmaf(v.y, w[1], a);
            a = fmaf(v.z, w[2], a);
            a = fmaf(v.w, w[3], a);
            acc[s] = a;
        }
    }

    // ---- reduce each acc[s] across the 8-lane iq group ----
    #pragma unroll
    for (int s = 0; s < 16; ++s) {
        float v = acc[s];
        v += __shfl_xor(v, 1, 8);
        v += __shfl_xor(v, 2, 8);
        v += __shfl_xor(v, 4, 8);
        acc[s] = v;
    }
    // lane iq keeps s=iq and s=iq+8 (static cndmask chains)
    float r0 = acc[0], r1 = acc[8];
    #pragma unroll
    for (int s = 1; s < 8; ++s) {
        r0 = (iq == s) ? acc[s]     : r0;
        r1 = (iq == s) ? acc[s + 8] : r1;
    }

    if (do_kl) {
        klw += __shfl_xor(klw, 1, 64);
        klw += __shfl_xor(klw, 2, 64);
        klw += __shfl_xor(klw, 4, 64);
        klw += __shfl_xor(klw, 8, 64);
        klw += __shfl_xor(klw, 16, 64);
        klw += __shfl_xor(klw, 32, 64);
    }

    __syncthreads();    // all input LDS reads done; safe to overlay

    const int col = wid * 8 + og;       // 0..63
    smem[iq * 72 + col]       = r0;     // res[s][col], stride 72 (2-way banks: free)
    smem[(iq + 8) * 72 + col] = r1;
    if (do_kl && lane == 0) smem[1200 + wid] = klw;

    if (blk == 0) {                      // kl_b: 1024 elems, 2 per thread
        float klb = 0.0f;
        #pragma unroll
        for (int h = 0; h < 2; ++h) {
            const int oo = tid + h * 512;
            const float sp = softplus_f(b_eta[oo]) + 1e-6f;
            const float m  = b_mu[oo];
            klb += -__logf(sp) + 0.5f * fmaf(sp, sp, m * m) - 0.5f;
        }
        klb += __shfl_xor(klb, 1, 64);
        klb += __shfl_xor(klb, 2, 64);
        klb += __shfl_xor(klb, 4, 64);
        klb += __shfl_xor(klb, 8, 64);
        klb += __shfl_xor(klb, 16, 64);
        klb += __shfl_xor(klb, 32, 64);
        if (lane == 0) smem[1208 + wid] = klb;
    }
    __syncthreads();

    // ---- coalesced stores with fused bias ----
    {
        const int s = tid >> 5, c = tid & 31;
        #pragma unroll
        for (int h = 0; h < 2; ++h) {
            const int ol = c + h * 32;
            const int oo = o_base + ol;
            const float bias = fmaf(softplus_f(b_eta[oo]) + 1e-6f,
                                    eps_b[(size_t)b * OUT_ + oo], b_mu[oo]);
            out[((size_t)s * B_ + b) * OUT_ + oo] = smem[s * 72 + ol] + bias;
        }
    }

    if (tid == 0 && do_kl) {
        float t = 0.0f;
        #pragma unroll
        for (int k = 0; k < 8; ++k) t += smem[1200 + k];
        atomicAdd(&kl[0], t);
    }
    if (tid == 64 && blk == 0) {
        float t = 0.0f;
        #pragma unroll
        for (int k = 0; k < 8; ++k) t += smem[1208 + k];
        atomicAdd(&kl[1], t);
    }
}

extern "C" void kernel_launch(void* const* d_in, const int* in_sizes, int n_in,
                              void* d_out, int out_size, void* d_ws, size_t ws_size,
                              hipStream_t stream)
{
    const float* input = (const float*)d_in[0];
    const float* w_mu  = (const float*)d_in[1];
    const float* w_eta = (const float*)d_in[2];
    const float* b_mu  = (const float*)d_in[3];
    const float* b_eta = (const float*)d_in[4];
    const float* eps_w = (const float*)d_in[5];
    const float* eps_b = (const float*)d_in[6];

    float* out = (float*)d_out;
    float* kl  = out + (size_t)S_ * B_ * OUT_;   // offsets 524288, 524289

    hipMemsetAsync(kl, 0, 2 * sizeof(float), stream);
    bpl_main_kernel<<<512, 512, 0, stream>>>(input, w_mu, w_eta, b_mu, b_eta,
                                             eps_w, eps_b, out, kl);
}